// Round 15
// baseline (128.077 us; speedup 1.0000x reference)
//
#include <hip/hip_runtime.h>
#include <hip/hip_bf16.h>

#define B_ 4
#define C_ 512
#define H_ 96
#define W_ 320
#define D_ 48
#define HW_ (H_*W_)

#define KC 32              // channels per chunk = MFMA K
#define NCHUNK (C_/KC)     // 16
#define WCOLS 112          // per-wave LDS cols: 32 L + 80 R (5 slots x 16)
#define CSTR 72            // bytes per LDS column (64B data + 8B pad; bank walk 18)
#define LDSB (WCOLS*CSTR)  // 8064 B — single wave, single buffer
#define NT 64              // ONE wave per block: no barriers in K-loop
#define NUW 224            // real staging units: 28 col-quads x 8 ch-quads
#define SIT 4              // 4 unit-slots/lane -> 16 loads/chunk (exact vmcnt)
#define EPS2 36            // epilogue row stride in floats (16B-aligned)
#define NBLK (B_*H_*10)    // 3840 blocks = 8 XCDs x 480 exactly

typedef __attribute__((ext_vector_type(8))) short bf16x8;
typedef __attribute__((ext_vector_type(4))) float f32x4;

__device__ __forceinline__ unsigned cvt2(float lo, float hi) {
  union { __hip_bfloat162 h2; unsigned u; } u;
  u.h2 = __float22bfloat162_rn(make_float2(lo, hi));   // v_cvt_pk_bf16_f32 (RNE)
  return u.u;
}
// Column-major [col][k] bf16, stride 72 B, no swizzle (R7/R10/R12-verified):
// 18*lc mod 32 bijects lc=0..15 onto the 16 even banks -> fragment reads
// (b64 pairs at col*72 + 16*lg, +8) sit exactly at the 4-access/bank floor.
__device__ __forceinline__ int ldsoff(int col, int q) {   // q = 8B k-granule
  return col * CSTR + (q << 3);
}

__global__ __launch_bounds__(NT, 1)   // allow a large VGPR budget: 2 staging sets
void cost_volume_mfma(const float* __restrict__ Lp,
                      const float* __restrict__ Rp,
                      float* __restrict__ out) {
  __shared__ __align__(16) char lds[LDSB];
  const int ln = threadIdx.x;
  // T1: bijective XCD-chunked swizzle (3840 % 8 == 0) — R11/R12-verified:
  // FETCH 455 -> 250 MB (R-halo re-reads hit the home XCD's 4MB L2).
  const int bid = blockIdx.x;
  const int wk = (bid & 7) * (NBLK / 8) + (bid >> 3);
  const int t2 = wk % 10;
  const int bh = wk / 10;
  const int b = bh / H_, h = bh % H_;
  const int lc = ln & 15;
  const int lg = (ln >> 4) & 3;
  const int m0 = 2 * t2;               // this wave owns m-tiles m0, m0+1

  // ---- staging unit descriptors: u -> (c4 = u%28, chq = u/28) ----
  // UNCONDITIONAL loads: u>=NUW clamps to unit 0 (same data, same dst ->
  // benign dup write); jn<0 clamps x to 0 (valid addr, written to a col slot
  // that bval excludes from compute). Exactly 16 vm-events per chunk.
  const float* spA[SIT];   // even chunks
  const float* spB[SIT];   // odd chunks
  int dstb[SIT];
#pragma unroll
  for (int it = 0; it < SIT; ++it) {
    const int u = ln + 64 * it;
    const int uc = (u < NUW) ? u : 0;
    const int c4 = uc % 28, chq = uc / 28;
    const int col = 4 * c4;
    int x;
    const float* bp;
    if (c4 < 8) { x = 16 * m0 + col; bp = Lp; }
    else {
      const int dnp = (c4 - 8) >> 2, jn = m0 + 1 - dnp;
      x = 16 * jn + 4 * ((c4 - 8) & 3);
      bp = Rp;
    }
    if (x < 0) x = 0;
    spA[it] = bp + ((size_t)(b * C_ + 4 * chq) * H_ + h) * W_ + x;
    spB[it] = spA[it] + (size_t)KC * HW_;   // set B starts at chunk 1
    dstb[it] = ldsoff(col, chq);
  }

  f32x4 srA[SIT][4], srB[SIT][4];   // two chunks in flight (128 VGPR, asm-pinned)

// Volatile asm loads: compiler cannot sink/elide/serialize them; position is
// pinned by the volatile chain + sched_barrier. Advances sp by 2 chunks.
#define SLOADX(sr, sp) do { \
  _Pragma("unroll") for (int it = 0; it < SIT; ++it) { \
    _Pragma("unroll") for (int l = 0; l < 4; ++l) \
      asm volatile("global_load_dwordx4 %0, %1, off" \
                   : "=v"(sr[it][l]) : "v"(sp[it] + (size_t)l * HW_)); \
    sp[it] += (size_t)2 * KC * HW_; \
  } \
  __builtin_amdgcn_sched_barrier(0); \
} while (0)

// Counted wait: ties the released set as "+v" outputs so every later use of
// sr dataflow-depends on the WAIT (not just the load) — the robust rule-#18
// ordering fix. N=16 leaves the other set's 16 loads in flight.
#define VMWAIT(sr, N) do { \
  asm volatile("s_waitcnt vmcnt(" #N ")" \
    : "+v"(sr[0][0]), "+v"(sr[0][1]), "+v"(sr[0][2]), "+v"(sr[0][3]), \
      "+v"(sr[1][0]), "+v"(sr[1][1]), "+v"(sr[1][2]), "+v"(sr[1][3]), \
      "+v"(sr[2][0]), "+v"(sr[2][1]), "+v"(sr[2][2]), "+v"(sr[2][3]), \
      "+v"(sr[3][0]), "+v"(sr[3][1]), "+v"(sr[3][2]), "+v"(sr[3][3]) \
    :: "memory"); \
  __builtin_amdgcn_sched_barrier(0); \
} while (0)

#define SWRITEX(sr) \
  _Pragma("unroll") for (int it = 0; it < SIT; ++it) { \
    char* p = lds + dstb[it]; \
    uint2 v; \
    v.x = cvt2(sr[it][0][0], sr[it][1][0]); v.y = cvt2(sr[it][2][0], sr[it][3][0]); \
    *(uint2*)(p) = v; \
    v.x = cvt2(sr[it][0][1], sr[it][1][1]); v.y = cvt2(sr[it][2][1], sr[it][3][1]); \
    *(uint2*)(p + CSTR) = v; \
    v.x = cvt2(sr[it][0][2], sr[it][1][2]); v.y = cvt2(sr[it][2][2], sr[it][3][2]); \
    *(uint2*)(p + 2 * CSTR) = v; \
    v.x = cvt2(sr[it][0][3], sr[it][1][3]); v.y = cvt2(sr[it][2][3], sr[it][3][3]); \
    *(uint2*)(p + 3 * CSTR) = v; \
  }

  // ---- fragment byte offsets (wave-local cols; R7-verified mapping) ----
  const int aoff0 = ldsoff(lc, 2 * lg);          // L tile m0
  const int aoff1 = ldsoff(16 + lc, 2 * lg);     // L tile m0+1
  int boff[5];
  bool bval[5];
#pragma unroll
  for (int dnp = 0; dnp < 5; ++dnp) {
    boff[dnp] = ldsoff(32 + 16 * dnp + lc, 2 * lg);
    bval[dnp] = (m0 + 1 - dnp) >= 0;
  }

  union FragU { uint2 h[2]; bf16x8 v; };
#define FREAD(fr, off) do { FragU _f; \
  _f.h[0] = *(const uint2*)(lds + (off)); \
  _f.h[1] = *(const uint2*)(lds + (off) + 8); fr = _f.v; } while (0)

  f32x4 acc[2][4];
#pragma unroll
  for (int ml = 0; ml < 2; ++ml)
#pragma unroll
    for (int dn = 0; dn < 4; ++dn) acc[ml][dn] = (f32x4){0.f, 0.f, 0.f, 0.f};

#define COMPUTE() do { \
    bf16x8 a0, a1; \
    FREAD(a0, aoff0); \
    FREAD(a1, aoff1); \
    bf16x8 bf[5]; \
    _Pragma("unroll") for (int dnp = 0; dnp < 5; ++dnp) \
      if (bval[dnp]) FREAD(bf[dnp], boff[dnp]); \
    _Pragma("unroll") for (int dn = 0; dn < 4; ++dn) { \
      if (bval[dn + 1]) \
        acc[0][dn] = __builtin_amdgcn_mfma_f32_16x16x32_bf16(a0, bf[dn + 1], acc[0][dn], 0, 0, 0); \
      if (bval[dn]) \
        acc[1][dn] = __builtin_amdgcn_mfma_f32_16x16x32_bf16(a1, bf[dn], acc[1][dn], 0, 0, 0); \
    } \
  } while (0)

  // ---- asm-pipelined K loop (single wave, zero barriers):
  // iter k: COMPUTE(k) -> vmcnt(16) [k+1 landed, k+2 rides] -> SWRITE(k+1)
  // -> SLOAD(k+3). Window per chunk ≈ 2 compute phases > HBM latency.
  // In-order DS: ds_reads of buf (COMPUTE) precede ds_writes (SWRITE). ----
  SLOADX(srA, spA);      // ch0          (spA -> ch2)
  VMWAIT(srA, 0);
  SWRITEX(srA);          // buf = ch0
  SLOADX(srB, spB);      // ch1 in flight (spB -> ch3)
  SLOADX(srA, spA);      // ch2 in flight (spA -> ch4)
  for (int k = 0; k < 14; k += 2) {
    COMPUTE();                       // ch k
    VMWAIT(srB, 16);                 // ch k+1 done; ch k+2 outstanding
    SWRITEX(srB);                    // buf = ch k+1
    SLOADX(srB, spB);                // ch k+3 (k<=12 -> ch<=15, valid)
    COMPUTE();                       // ch k+1
    VMWAIT(srA, 16);                 // ch k+2 done; ch k+3 outstanding
    SWRITEX(srA);                    // buf = ch k+2
    if (k < 12) SLOADX(srA, spA);    // ch k+4 (skip ghost ch16 at k=12)
  }
  COMPUTE();                         // ch14
  VMWAIT(srB, 0);                    // drain ch15
  SWRITEX(srB);                      // buf = ch15
  COMPUTE();                         // ch15

  // ---- epilogue: per-wave transpose through LDS -> coalesced stores ----
  __syncthreads();
  float* ep = (float*)lds;                 // [48][EPS2] = 6912 B (fits in 8064)
#pragma unroll
  for (int e = 0; e < (D_ * EPS2 + NT - 1) / NT; ++e) {
    const int i = ln + NT * e;
    if (i < D_ * EPS2) ep[i] = 0.f;
  }
  __syncthreads();
  const float scale = 1.f / 512.f;
#pragma unroll
  for (int ml = 0; ml < 2; ++ml) {
#pragma unroll
    for (int dn = 0; dn < 4; ++dn) {
      if ((m0 + ml - dn) >= 0) {
#pragma unroll
        for (int q = 0; q < 4; ++q) {
          const int i = 4 * lg + q;        // C/D row = 4*(lane>>4) + reg
          const int d = 16 * dn + i - lc;  // d = w - w'
          if (d >= 0 && d < D_)
            ep[d * EPS2 + 16 * ml + i] = acc[ml][dn][q] * scale;
        }
      }
    }
  }
  __syncthreads();
  // 48 d-rows x 8 float4 (32 w-cols) = 384 units = 6 per lane
#pragma unroll
  for (int e = 0; e < 6; ++e) {
    const int u = ln + NT * e;
    const int d = u >> 3, c4 = u & 7;
    const float4 v = *(const float4*)(ep + d * EPS2 + 4 * c4);
    float* o = out + (((size_t)b * D_ + d) * H_ + h) * W_ + 16 * m0 + 4 * c4;
    *(float4*)o = v;
  }
}

extern "C" void kernel_launch(void* const* d_in, const int* in_sizes, int n_in,
                              void* d_out, int out_size, void* d_ws, size_t ws_size,
                              hipStream_t stream) {
  const float* left  = (const float*)d_in[0];
  const float* right = (const float*)d_in[1];
  float* outp = (float*)d_out;
  cost_volume_mfma<<<dim3(NBLK), dim3(NT), 0, stream>>>(left, right, outp);
}